// Round 14
// baseline (186.198 us; speedup 1.0000x reference)
//
#include <hip/hip_runtime.h>

constexpr int NB = 10, H = 128;
constexpr int M = 64 * 1024;             // B*A rows
constexpr long SL = (long)M * H;         // elems per [M,H] matrix

typedef __attribute__((ext_vector_type(8))) short s16x8;
typedef __attribute__((ext_vector_type(4))) float f32x4;

__device__ __forceinline__ ushort f2b(float f) {
    union { float f; uint u; } v; v.f = f;
    uint u = v.u;
    uint r = u + 0x7fffu + ((u >> 16) & 1u);
    return (ushort)(r >> 16);
}
__device__ __forceinline__ float b2f(ushort u) {
    union { uint u; float f; } v; v.u = ((uint)u) << 16; return v.f;
}

// XCD-chunked bijective swizzle (sub-grid % 8 == 0)
__device__ __forceinline__ int swz(int bid, int cpx) {
    return (bid & 7) * cpx + (bid >> 3);
}

// ---------------------------------------------------------------------------
// GEMM body (K<=128): wave owns 32 cols, w[2][NC]<=32 VGPR — resident at the
// 64-reg tier (verified R8: VGPR=64).  Plain bf16 output only.
// ---------------------------------------------------------------------------
template<int NC>
__device__ __forceinline__ void gemm_body(
    int tg, const ushort* __restrict__ Abf, const ushort* __restrict__ WT,
    ushort* __restrict__ Cb)
{
    constexpr int K = NC * 32;
    const int lane = threadIdx.x & 63, wid = threadIdx.x >> 6;
    const int l15 = lane & 15, g = lane >> 4;

    s16x8 w[2][NC];
    #pragma unroll
    for (int ct = 0; ct < 2; ++ct)
        #pragma unroll
        for (int kc = 0; kc < NC; ++kc)
            w[ct][kc] = *(const s16x8*)(WT + (size_t)((2 * wid + ct) * 16 + l15) * K + kc * 32 + g * 8);

    #pragma unroll
    for (int i = 0; i < 4; ++i) {
        const int m0 = (tg * 4 + i) * 16;
        s16x8 ac[NC];
        #pragma unroll
        for (int kc = 0; kc < NC; ++kc)
            ac[kc] = *(const s16x8*)(Abf + (size_t)(m0 + l15) * K + kc * 32 + g * 8);

        f32x4 acc[2];
        #pragma unroll
        for (int ct = 0; ct < 2; ++ct) acc[ct] = (f32x4){0.f, 0.f, 0.f, 0.f};
        #pragma unroll
        for (int kc = 0; kc < NC; ++kc)
            #pragma unroll
            for (int ct = 0; ct < 2; ++ct)
                acc[ct] = __builtin_amdgcn_mfma_f32_16x16x32_bf16(ac[kc], w[ct][kc], acc[ct], 0, 0, 0);

        #pragma unroll
        for (int ct = 0; ct < 2; ++ct) {
            const int col = (2 * wid + ct) * 16 + l15;
            #pragma unroll
            for (int r = 0; r < 4; ++r)
                Cb[(size_t)(m0 + 4 * g + r) * H + col] = f2b(acc[ct][r]);
        }
    }
}

// ---------------------------------------------------------------------------
// Composed-U1 body: out = AF@Wu1a + SATOM@Wc + FBS8@W2c   (K=288, 9 chunks)
// (weight-pin kept from R13 — best-measured config)
// ---------------------------------------------------------------------------
template<bool OF32>
__device__ __forceinline__ void u1f_body(
    int tg, const ushort* __restrict__ AF, const ushort* __restrict__ SATOM,
    const ushort* __restrict__ FBSb, const ushort* __restrict__ WT,
    float* __restrict__ Cf, ushort* __restrict__ Cb)
{
    const int lane = threadIdx.x & 63, wid = threadIdx.x >> 6;
    const int l15 = lane & 15, g = lane >> 4;

    s16x8 w[2][9];
    #pragma unroll
    for (int ct = 0; ct < 2; ++ct)
        #pragma unroll
        for (int kc = 0; kc < 9; ++kc)
            w[ct][kc] = *(const s16x8*)(WT + (size_t)((2 * wid + ct) * 16 + l15) * 288 + kc * 32 + g * 8);
    #pragma unroll
    for (int ct = 0; ct < 2; ++ct)
        #pragma unroll
        for (int kc = 0; kc < 9; ++kc)
            asm volatile("" : "+v"(w[ct][kc]));

    #pragma unroll
    for (int i = 0; i < 4; ++i) {
        const int m0 = (tg * 4 + i) * 16;
        const size_t rb = (size_t)(m0 + l15) * H + g * 8;
        s16x8 ac[9];
        #pragma unroll
        for (int kc = 0; kc < 4; ++kc) {
            ac[kc]     = *(const s16x8*)(AF    + rb + kc * 32);
            ac[kc + 4] = *(const s16x8*)(SATOM + rb + kc * 32);
        }
        ac[8] = (s16x8){0,0,0,0,0,0,0,0};
        if (g == 0) ac[8] = *(const s16x8*)(FBSb + (size_t)(m0 + l15) * 8);

        f32x4 acc[2];
        #pragma unroll
        for (int ct = 0; ct < 2; ++ct) acc[ct] = (f32x4){0.f, 0.f, 0.f, 0.f};
        #pragma unroll
        for (int kc = 0; kc < 9; ++kc)
            #pragma unroll
            for (int ct = 0; ct < 2; ++ct)
                acc[ct] = __builtin_amdgcn_mfma_f32_16x16x32_bf16(ac[kc], w[ct][kc], acc[ct], 0, 0, 0);

        #pragma unroll
        for (int ct = 0; ct < 2; ++ct) {
            const int col = (2 * wid + ct) * 16 + l15;
            #pragma unroll
            for (int r = 0; r < 4; ++r) {
                const size_t o = (size_t)(m0 + 4 * g + r) * H + col;
                if constexpr (OF32) Cf[o] = acc[ct][r]; else Cb[o] = f2b(acc[ct][r]);
            }
        }
    }
}

template<bool OF32>
__global__ __launch_bounds__(256, 3) void u1f(
    const ushort* __restrict__ AF, const ushort* __restrict__ SATOM,
    const ushort* __restrict__ FBSb, const ushort* __restrict__ WT,
    float* __restrict__ Cf, ushort* __restrict__ Cb)
{
    u1f_body<OF32>(swz(blockIdx.x, 128), AF, SATOM, FBSb, WT, Cf, Cb);
}

// K5: [0,1024): ATW = AF @ WTna ; [1024,2048): SLF = AF @ WTslf  (co-run)
__global__ __launch_bounds__(256, 4) void k5_atw_slf(
    const ushort* __restrict__ AF, const ushort* __restrict__ WTna,
    const ushort* __restrict__ WTslf, ushort* __restrict__ ATW,
    ushort* __restrict__ SLF)
{
    if (blockIdx.x < 1024)
        gemm_body<4>(swz(blockIdx.x, 128), AF, WTna, ATW);
    else
        gemm_body<4>(swz(blockIdx.x - 1024, 128), AF, WTslf, SLF);
}

// ---------------------------------------------------------------------------
// SATOM gather: SATOM[m][:] = sum_{nb<nnb} AF[b, ag[m,nb]][:]  (bf16)
// ---------------------------------------------------------------------------
__global__ __launch_bounds__(256, 8) void gather_satom(
    const ushort* __restrict__ AF, const int* __restrict__ ag,
    const int* __restrict__ nn, ushort* __restrict__ SATOM)
{
    const int bid = swz(blockIdx.x, 512);
    const int m  = bid * 16 + (threadIdx.x >> 4);
    const int c8 = (threadIdx.x & 15) * 8;
    const int b  = m >> 10;
    const int nnb = nn[m];
    const ushort* AFb = AF + ((size_t)b << 10) * H + c8;
    const int* agm = ag + (size_t)m * NB;

    int2 iv0 = *(const int2*)(agm + 0);
    int2 iv1 = *(const int2*)(agm + 2);
    int2 iv2 = *(const int2*)(agm + 4);
    int2 iv3 = *(const int2*)(agm + 6);
    int2 iv4 = *(const int2*)(agm + 8);

    float sacc[8];
    #pragma unroll
    for (int i = 0; i < 8; ++i) sacc[i] = 0.f;

    #define GS_STEP(nb, ia)                                              \
    if ((nb) < nnb) {                                                    \
        s16x8 av = *(const s16x8*)(AFb + (size_t)(ia) * H);              \
        _Pragma("unroll")                                                \
        for (int i = 0; i < 8; ++i) sacc[i] += b2f((ushort)av[i]);       \
    }
    GS_STEP(0, iv0.x) GS_STEP(1, iv0.y)
    GS_STEP(2, iv1.x) GS_STEP(3, iv1.y)
    GS_STEP(4, iv2.x) GS_STEP(5, iv2.y)
    GS_STEP(6, iv3.x) GS_STEP(7, iv3.y)
    GS_STEP(8, iv4.x) GS_STEP(9, iv4.y)
    #undef GS_STEP

    s16x8 so;
    #pragma unroll
    for (int i = 0; i < 8; ++i) so[i] = (short)f2b(sacc[i]);
    *(s16x8*)(SATOM + (size_t)m * H + c8) = so;
}

// ---------------------------------------------------------------------------
// Last-depth gather v2: SATl (bf16) and
//   out0[m][c8..] = (sum_nb ATW[ag]*HB[bg]) * b2f(SLF[m][c8..]) * nmask[m]
// (the kernel-output product applied at the already-vectorized write)
// ---------------------------------------------------------------------------
__global__ __launch_bounds__(256, 4) void gather_last2(
    const ushort* __restrict__ AF, const ushort* __restrict__ ATW,
    const ushort* __restrict__ HB, const ushort* __restrict__ SLF,
    const float* __restrict__ nmask, const int* __restrict__ ag,
    const int* __restrict__ bg, const int* __restrict__ nn,
    ushort* __restrict__ SATOM, float* __restrict__ out0)
{
    const int bid = swz(blockIdx.x, 512);
    const int m  = bid * 16 + (threadIdx.x >> 4);
    const int c8 = (threadIdx.x & 15) * 8;
    const int b  = m >> 10;
    const int nnb = nn[m];
    const ushort* AFb  = AF  + ((size_t)b << 10) * H + c8;
    const ushort* ATWb = ATW + ((size_t)b << 10) * H + c8;
    const ushort* HBb  = HB  + ((size_t)b << 11) * H + c8;   // E = 2048
    const int* agm = ag + (size_t)m * NB;
    const int* bgm = bg + (size_t)m * NB;

    int2 ia0 = *(const int2*)(agm + 0), ib0 = *(const int2*)(bgm + 0);
    int2 ia1 = *(const int2*)(agm + 2), ib1 = *(const int2*)(bgm + 2);
    int2 ia2 = *(const int2*)(agm + 4), ib2 = *(const int2*)(bgm + 4);
    int2 ia3 = *(const int2*)(agm + 6), ib3 = *(const int2*)(bgm + 6);
    int2 ia4 = *(const int2*)(agm + 8), ib4 = *(const int2*)(bgm + 8);

    float sacc[8], facc[8];
    #pragma unroll
    for (int i = 0; i < 8; ++i) { sacc[i] = 0.f; facc[i] = 0.f; }

    #define GL_STEP(nb, ia, ib)                                          \
    if ((nb) < nnb) {                                                    \
        s16x8 av = *(const s16x8*)(AFb  + (size_t)(ia) * H);             \
        s16x8 tv = *(const s16x8*)(ATWb + (size_t)(ia) * H);             \
        s16x8 hv = *(const s16x8*)(HBb  + (size_t)(ib) * H);             \
        _Pragma("unroll")                                                \
        for (int i = 0; i < 8; ++i) {                                    \
            sacc[i] += b2f((ushort)av[i]);                               \
            facc[i] += b2f((ushort)tv[i]) * b2f((ushort)hv[i]);          \
        }                                                                \
    }
    GL_STEP(0, ia0.x, ib0.x) GL_STEP(1, ia0.y, ib0.y)
    GL_STEP(2, ia1.x, ib1.x) GL_STEP(3, ia1.y, ib1.y)
    GL_STEP(4, ia2.x, ib2.x) GL_STEP(5, ia2.y, ib2.y)
    GL_STEP(6, ia3.x, ib3.x) GL_STEP(7, ia3.y, ib3.y)
    GL_STEP(8, ia4.x, ib4.x) GL_STEP(9, ia4.y, ib4.y)
    #undef GL_STEP

    s16x8 so;
    #pragma unroll
    for (int i = 0; i < 8; ++i) so[i] = (short)f2b(sacc[i]);
    *(s16x8*)(SATOM + (size_t)m * H + c8) = so;

    const float nm = nmask[m];
    s16x8 sv = *(const s16x8*)(SLF + (size_t)m * H + c8);
    f32x4 lo, hi;
    #pragma unroll
    for (int i = 0; i < 4; ++i) {
        lo[i] = facc[i]     * b2f((ushort)sv[i])     * nm;
        hi[i] = facc[i + 4] * b2f((ushort)sv[i + 4]) * nm;
    }
    *(f32x4*)(out0 + (size_t)m * H + c8)     = lo;
    *(f32x4*)(out0 + (size_t)m * H + c8 + 4) = hi;
}

// ---------------------------------------------------------------------------
// FA GEMM body reading input_atom f32 directly (K=96 logical, cols>=82 zero)
// ---------------------------------------------------------------------------
__device__ __forceinline__ void fa_body(
    int tg, const float* __restrict__ ia, const float* __restrict__ Wa,
    ushort* __restrict__ Cb)
{
    const int lane = threadIdx.x & 63, wid = threadIdx.x >> 6;
    const int l15 = lane & 15, g = lane >> 4;

    s16x8 w[2][3];
    #pragma unroll
    for (int ct = 0; ct < 2; ++ct) {
        const int n = (2 * wid + ct) * 16 + l15;
        #pragma unroll
        for (int kc = 0; kc < 3; ++kc) {
            s16x8 wv;
            #pragma unroll
            for (int i = 0; i < 8; ++i) {
                const int k = kc * 32 + g * 8 + i;
                wv[i] = (short)(k < 82 ? f2b(Wa[k * H + n]) : 0);
            }
            w[ct][kc] = wv;
        }
    }

    #pragma unroll
    for (int t = 0; t < 4; ++t) {
        const int m0 = (tg * 4 + t) * 16;
        const float* row = ia + (size_t)(m0 + l15) * 82;
        s16x8 a[3];
        #pragma unroll
        for (int kc = 0; kc < 3; ++kc) {
            #pragma unroll
            for (int p = 0; p < 4; ++p) {
                const int k = kc * 32 + g * 8 + 2 * p;     // even; boundary 82 even
                float2 v = (k < 82) ? *(const float2*)(row + k)
                                    : make_float2(0.f, 0.f);
                a[kc][2 * p]     = (short)f2b(v.x);
                a[kc][2 * p + 1] = (short)f2b(v.y);
            }
        }
        f32x4 acc[2];
        #pragma unroll
        for (int ct = 0; ct < 2; ++ct) acc[ct] = (f32x4){0.f, 0.f, 0.f, 0.f};
        #pragma unroll
        for (int kc = 0; kc < 3; ++kc)
            #pragma unroll
            for (int ct = 0; ct < 2; ++ct)
                acc[ct] = __builtin_amdgcn_mfma_f32_16x16x32_bf16(a[kc], w[ct][kc], acc[ct], 0, 0, 0);
        #pragma unroll
        for (int ct = 0; ct < 2; ++ct) {
            const int col = (2 * wid + ct) * 16 + l15;
            #pragma unroll
            for (int r = 0; r < 4; ++r)
                Cb[(size_t)(m0 + 4 * g + r) * H + col] = f2b(acc[ct][r]);
        }
    }
}

// ---------------------------------------------------------------------------
// K0: block-range-split {FA gemm | weights compose | FBS8 | HB}
//  [0,1024): FA  [1024,1296): weights  [1296,1552): FBS  [1552,9744): HB
//  WTs layout: WTna[128][128] | WTslf[128][128] | WTu1f[128][288]
// ---------------------------------------------------------------------------
__global__ __launch_bounds__(256, 4) void k0_prep_fa(
    const float* __restrict__ ia, const float* __restrict__ Wa,
    const float* __restrict__ Wna, const float* __restrict__ Ws,
    const float* __restrict__ Wu2, const float* __restrict__ bu2,
    const float* __restrict__ Wu1, const float* __restrict__ bu1,
    const float* __restrict__ bond, const int* __restrict__ bg,
    const int* __restrict__ nn, const float* __restrict__ Wnb,
    ushort* __restrict__ AF0, ushort* __restrict__ WTs,
    ushort* __restrict__ FBSb, ushort* __restrict__ HB)
{
    const int bid = blockIdx.x;
    if (bid < 1024) {
        fa_body(swz(bid, 128), ia, Wa, AF0);
    } else if (bid < 1296) {
        int t = (bid - 1024) * 256 + threadIdx.x;
        const int tid = t;
        if (t < 128 * 128) { int n = t / 128, k = t % 128;
            WTs[tid] = f2b(Wna[k * H + n]); return; }
        t -= 128 * 128;
        if (t < 128 * 128) { int n = t / 128, k = t % 128;
            WTs[tid] = f2b(Ws[k * H + n]); return; }
        t -= 128 * 128;
        {
            const int n = t / 288, k = t % 288;
            float v = 0.f;
            if (k < 128) {
                v = Wu1[k * H + n];
            } else if (k < 256) {
                const int kk = k - 128;
                float s = 0.f;
                for (int j = 0; j < 128; ++j) s += Wu2[kk * H + j] * Wu1[(128 + j) * H + n];
                v = s;
            } else {
                const int j = k - 256;
                if (j < 6) {
                    float s = 0.f;
                    for (int q = 0; q < 128; ++q) s += Wu2[(128 + j) * H + q] * Wu1[(128 + q) * H + n];
                    v = s;
                } else if (j == 6) {
                    float s = 0.f;
                    for (int q = 0; q < 128; ++q) s += bu2[q] * Wu1[(128 + q) * H + n];
                    v = s;
                } else if (j == 7) {
                    v = bu1[n];
                }
            }
            WTs[tid] = f2b(v);
            return;
        }
    } else if (bid < 1552) {
        // FBS8[m][8] = bf16[ sum_nb bond[bg[m,nb]][0..5], num_nbs, 1 ]
        const int m = (bid - 1296) * 256 + threadIdx.x;
        const int b = m >> 10;
        const int nnb = nn[m];
        float s[6] = {0,0,0,0,0,0};
        for (int nb = 0; nb < nnb; ++nb) {
            const int ib = bg[m * NB + nb];
            const float* fb = bond + ((size_t)(b << 11) + (size_t)ib) * 6;
            #pragma unroll
            for (int j = 0; j < 6; ++j) s[j] += fb[j];
        }
        s16x8 o;
        #pragma unroll
        for (int j = 0; j < 6; ++j) o[j] = (short)f2b(s[j]);
        o[6] = (short)f2b((float)nnb);
        o[7] = (short)f2b(1.0f);
        *(s16x8*)(FBSb + (size_t)m * 8) = o;
    } else {
        // HB[b][e][:] = bond[b,e,:] @ W_nei_bond  (bf16)
        const int t = (bid - 1552) * 256 + threadIdx.x;    // B*E*16
        const int r = t >> 4, c8 = (t & 15) * 8;
        const float* fb = bond + (size_t)r * 6;
        const float2 f01 = *(const float2*)fb;
        const float2 f23 = *(const float2*)(fb + 2);
        const float2 f45 = *(const float2*)(fb + 4);
        s16x8 o;
        #pragma unroll
        for (int i = 0; i < 8; ++i) {
            const int c = c8 + i;
            const float v = f01.x * Wnb[0 * H + c] + f01.y * Wnb[1 * H + c]
                          + f23.x * Wnb[2 * H + c] + f23.y * Wnb[3 * H + c]
                          + f45.x * Wnb[4 * H + c] + f45.y * Wnb[5 * H + c];
            o[i] = (short)f2b(v);
        }
        *(s16x8*)(HB + (size_t)r * H + c8) = o;
    }
}

// ---------------------------------------------------------------------------
extern "C" void kernel_launch(void* const* d_in, const int* in_sizes, int n_in,
                              void* d_out, int out_size, void* d_ws, size_t ws_size,
                              hipStream_t stream)
{
    (void)in_sizes; (void)n_in; (void)out_size; (void)ws_size;

    const float* input_atom = (const float*)d_in[0];
    const float* input_bond = (const float*)d_in[1];
    const int*   atom_graph = (const int*)d_in[2];
    const int*   bond_graph = (const int*)d_in[3];
    const int*   num_nbs    = (const int*)d_in[4];
    const float* node_mask  = (const float*)d_in[5];
    const float* W_atom     = (const float*)d_in[6];
    const float* W_nei_atom = (const float*)d_in[7];
    const float* W_nei_bond = (const float*)d_in[8];
    const float* W_self     = (const float*)d_in[9];
    const float* W_U2       = (const float*)d_in[10];
    const float* b_U2       = (const float*)d_in[11];
    const float* W_U1       = (const float*)d_in[12];
    const float* b_U1       = (const float*)d_in[13];

    char* ws = (char*)d_ws;
    const size_t MB = 1024 * 1024;
    ushort* AF0   = (ushort*)(ws);               // [0,16) MB
    ushort* AF1   = (ushort*)(ws + 16 * MB);     // [16,32) MB (SLF at last depth)
    ushort* SATw  = (ushort*)(ws + 32 * MB);     // [32,48) MB (ATW at last depth)
    ushort* ATW   = SATw;
    ushort* HB    = (ushort*)(ws + 64 * MB);     // [64,96) MB
    ushort* SATl  = (ushort*)(ws + 96 * MB);     // [96,112) MB
    ushort* FBSb  = (ushort*)(ws + 112 * MB);    // 1 MB
    ushort* WTs_  = (ushort*)(ws + 113 * MB);    // ~140 KB

    ushort* WTna  = WTs_;                        // [128][128]
    ushort* WTslf = WTna  + 128 * 128;           // [128][128]
    ushort* WTu1f = WTslf + 128 * 128;           // [128][288]

    float*  out0  = (float*)d_out;               // kernel [M][128] f32
    float*  out1  = out0 + SL;                   // atom_features [M][128] f32
    ushort* SLF   = AF1;                         // AF@Wslf (bf16), AF1 dead

    // K0: FA gemm || weights compose || FBS || HB
    k0_prep_fa<<<9744, 256, 0, stream>>>(input_atom, W_atom, W_nei_atom,
                                         W_self, W_U2, b_U2, W_U1, b_U1,
                                         input_bond, bond_graph, num_nbs,
                                         W_nei_bond, AF0, WTs_, FBSb, HB);

    // depth 0
    gather_satom<<<4096, 256, 0, stream>>>(AF0, atom_graph, num_nbs, SATw);
    u1f<false><<<1024, 256, 0, stream>>>(AF0, SATw, FBSb, WTu1f, nullptr, AF1);
    // depth 1
    gather_satom<<<4096, 256, 0, stream>>>(AF1, atom_graph, num_nbs, SATw);
    u1f<false><<<1024, 256, 0, stream>>>(AF1, SATw, FBSb, WTu1f, nullptr, AF0);

    // ---- last depth (AF = AF0; AF1 dead -> SLF; SATw -> ATW) ----
    // K5: ATW = AF0 @ Wna  ||  SLF = AF0 @ Wslf   (independent, co-run)
    k5_atw_slf<<<2048, 256, 0, stream>>>(AF0, WTna, WTslf, ATW, SLF);
    // SATl = gather(AF0); out0 = FNEI * SLF * nmask  (fused at the write)
    gather_last2<<<4096, 256, 0, stream>>>(AF0, ATW, HB, SLF, node_mask,
                                           atom_graph, bond_graph, num_nbs,
                                           SATl, out0);
    // atom_features -> out1 (f32)
    u1f<true><<<1024, 256, 0, stream>>>(AF0, SATl, FBSb, WTu1f, out1, nullptr);
}

// Round 15
// 177.933 us; speedup vs baseline: 1.0464x; 1.0464x over previous
//
#include <hip/hip_runtime.h>

constexpr int NB = 10, H = 128;
constexpr int M = 64 * 1024;             // B*A rows
constexpr long SL = (long)M * H;         // elems per [M,H] matrix

typedef __attribute__((ext_vector_type(8))) short s16x8;
typedef __attribute__((ext_vector_type(4))) float f32x4;

__device__ __forceinline__ ushort f2b(float f) {
    union { float f; uint u; } v; v.f = f;
    uint u = v.u;
    uint r = u + 0x7fffu + ((u >> 16) & 1u);
    return (ushort)(r >> 16);
}
__device__ __forceinline__ float b2f(ushort u) {
    union { uint u; float f; } v; v.u = ((uint)u) << 16; return v.f;
}

// XCD-chunked bijective swizzle (sub-grid % 8 == 0)
__device__ __forceinline__ int swz(int bid, int cpx) {
    return (bid & 7) * cpx + (bid >> 3);
}

// ---------------------------------------------------------------------------
// GEMM body (K<=128): wave owns 32 cols, w[2][NC]<=32 VGPR — resident at the
// 64-reg tier.  Plain bf16 output only.
// ---------------------------------------------------------------------------
template<int NC>
__device__ __forceinline__ void gemm_body(
    int tg, const ushort* __restrict__ Abf, const ushort* __restrict__ WT,
    ushort* __restrict__ Cb)
{
    constexpr int K = NC * 32;
    const int lane = threadIdx.x & 63, wid = threadIdx.x >> 6;
    const int l15 = lane & 15, g = lane >> 4;

    s16x8 w[2][NC];
    #pragma unroll
    for (int ct = 0; ct < 2; ++ct)
        #pragma unroll
        for (int kc = 0; kc < NC; ++kc)
            w[ct][kc] = *(const s16x8*)(WT + (size_t)((2 * wid + ct) * 16 + l15) * K + kc * 32 + g * 8);

    #pragma unroll
    for (int i = 0; i < 4; ++i) {
        const int m0 = (tg * 4 + i) * 16;
        s16x8 ac[NC];
        #pragma unroll
        for (int kc = 0; kc < NC; ++kc)
            ac[kc] = *(const s16x8*)(Abf + (size_t)(m0 + l15) * K + kc * 32 + g * 8);

        f32x4 acc[2];
        #pragma unroll
        for (int ct = 0; ct < 2; ++ct) acc[ct] = (f32x4){0.f, 0.f, 0.f, 0.f};
        #pragma unroll
        for (int kc = 0; kc < NC; ++kc)
            #pragma unroll
            for (int ct = 0; ct < 2; ++ct)
                acc[ct] = __builtin_amdgcn_mfma_f32_16x16x32_bf16(ac[kc], w[ct][kc], acc[ct], 0, 0, 0);

        #pragma unroll
        for (int ct = 0; ct < 2; ++ct) {
            const int col = (2 * wid + ct) * 16 + l15;
            #pragma unroll
            for (int r = 0; r < 4; ++r)
                Cb[(size_t)(m0 + 4 * g + r) * H + col] = f2b(acc[ct][r]);
        }
    }
}

// ---------------------------------------------------------------------------
// Composed-U1 body: out = AF@Wu1a + SATOM@Wc + FBS8@W2c   (K=288, 9 chunks)
// ---------------------------------------------------------------------------
template<bool OF32>
__device__ __forceinline__ void u1f_body(
    int tg, const ushort* __restrict__ AF, const ushort* __restrict__ SATOM,
    const ushort* __restrict__ FBSb, const ushort* __restrict__ WT,
    float* __restrict__ Cf, ushort* __restrict__ Cb)
{
    const int lane = threadIdx.x & 63, wid = threadIdx.x >> 6;
    const int l15 = lane & 15, g = lane >> 4;

    s16x8 w[2][9];
    #pragma unroll
    for (int ct = 0; ct < 2; ++ct)
        #pragma unroll
        for (int kc = 0; kc < 9; ++kc)
            w[ct][kc] = *(const s16x8*)(WT + (size_t)((2 * wid + ct) * 16 + l15) * 288 + kc * 32 + g * 8);
    #pragma unroll
    for (int ct = 0; ct < 2; ++ct)
        #pragma unroll
        for (int kc = 0; kc < 9; ++kc)
            asm volatile("" : "+v"(w[ct][kc]));

    #pragma unroll
    for (int i = 0; i < 4; ++i) {
        const int m0 = (tg * 4 + i) * 16;
        const size_t rb = (size_t)(m0 + l15) * H + g * 8;
        s16x8 ac[9];
        #pragma unroll
        for (int kc = 0; kc < 4; ++kc) {
            ac[kc]     = *(const s16x8*)(AF    + rb + kc * 32);
            ac[kc + 4] = *(const s16x8*)(SATOM + rb + kc * 32);
        }
        ac[8] = (s16x8){0,0,0,0,0,0,0,0};
        if (g == 0) ac[8] = *(const s16x8*)(FBSb + (size_t)(m0 + l15) * 8);

        f32x4 acc[2];
        #pragma unroll
        for (int ct = 0; ct < 2; ++ct) acc[ct] = (f32x4){0.f, 0.f, 0.f, 0.f};
        #pragma unroll
        for (int kc = 0; kc < 9; ++kc)
            #pragma unroll
            for (int ct = 0; ct < 2; ++ct)
                acc[ct] = __builtin_amdgcn_mfma_f32_16x16x32_bf16(ac[kc], w[ct][kc], acc[ct], 0, 0, 0);

        #pragma unroll
        for (int ct = 0; ct < 2; ++ct) {
            const int col = (2 * wid + ct) * 16 + l15;
            #pragma unroll
            for (int r = 0; r < 4; ++r) {
                const size_t o = (size_t)(m0 + 4 * g + r) * H + col;
                if constexpr (OF32) Cf[o] = acc[ct][r]; else Cb[o] = f2b(acc[ct][r]);
            }
        }
    }
}

template<bool OF32>
__global__ __launch_bounds__(256, 3) void u1f(
    const ushort* __restrict__ AF, const ushort* __restrict__ SATOM,
    const ushort* __restrict__ FBSb, const ushort* __restrict__ WT,
    float* __restrict__ Cf, ushort* __restrict__ Cb)
{
    u1f_body<OF32>(swz(blockIdx.x, 128), AF, SATOM, FBSb, WT, Cf, Cb);
}

// K5: [0,1024): ATW = AF @ WTna ; [1024,2048): SLF = AF @ WTslf  (co-run)
__global__ __launch_bounds__(256, 4) void k5_atw_slf(
    const ushort* __restrict__ AF, const ushort* __restrict__ WTna,
    const ushort* __restrict__ WTslf, ushort* __restrict__ ATW,
    ushort* __restrict__ SLF)
{
    if (blockIdx.x < 1024)
        gemm_body<4>(swz(blockIdx.x, 128), AF, WTna, ATW);
    else
        gemm_body<4>(swz(blockIdx.x - 1024, 128), AF, WTslf, SLF);
}

// ---------------------------------------------------------------------------
// SATOM gather: SATOM[m][:] = sum_{nb<nnb} AF[b, ag[m,nb]][:]  (bf16)
// ---------------------------------------------------------------------------
__global__ __launch_bounds__(256, 8) void gather_satom(
    const ushort* __restrict__ AF, const int* __restrict__ ag,
    const int* __restrict__ nn, ushort* __restrict__ SATOM)
{
    const int bid = swz(blockIdx.x, 512);
    const int m  = bid * 16 + (threadIdx.x >> 4);
    const int c8 = (threadIdx.x & 15) * 8;
    const int b  = m >> 10;
    const int nnb = nn[m];
    const ushort* AFb = AF + ((size_t)b << 10) * H + c8;
    const int* agm = ag + (size_t)m * NB;

    int2 iv0 = *(const int2*)(agm + 0);
    int2 iv1 = *(const int2*)(agm + 2);
    int2 iv2 = *(const int2*)(agm + 4);
    int2 iv3 = *(const int2*)(agm + 6);
    int2 iv4 = *(const int2*)(agm + 8);

    float sacc[8];
    #pragma unroll
    for (int i = 0; i < 8; ++i) sacc[i] = 0.f;

    #define GS_STEP(nb, ia)                                              \
    if ((nb) < nnb) {                                                    \
        s16x8 av = *(const s16x8*)(AFb + (size_t)(ia) * H);              \
        _Pragma("unroll")                                                \
        for (int i = 0; i < 8; ++i) sacc[i] += b2f((ushort)av[i]);       \
    }
    GS_STEP(0, iv0.x) GS_STEP(1, iv0.y)
    GS_STEP(2, iv1.x) GS_STEP(3, iv1.y)
    GS_STEP(4, iv2.x) GS_STEP(5, iv2.y)
    GS_STEP(6, iv3.x) GS_STEP(7, iv3.y)
    GS_STEP(8, iv4.x) GS_STEP(9, iv4.y)
    #undef GS_STEP

    s16x8 so;
    #pragma unroll
    for (int i = 0; i < 8; ++i) so[i] = (short)f2b(sacc[i]);
    *(s16x8*)(SATOM + (size_t)m * H + c8) = so;
}

// ---------------------------------------------------------------------------
// Last-depth gather v2: SATl (bf16) and
//   out0[m][c8..] = (sum_nb ATW[ag]*HB[bg]) * b2f(SLF[m][c8..]) * nmask[m]
// ---------------------------------------------------------------------------
__global__ __launch_bounds__(256, 4) void gather_last2(
    const ushort* __restrict__ AF, const ushort* __restrict__ ATW,
    const ushort* __restrict__ HB, const ushort* __restrict__ SLF,
    const float* __restrict__ nmask, const int* __restrict__ ag,
    const int* __restrict__ bg, const int* __restrict__ nn,
    ushort* __restrict__ SATOM, float* __restrict__ out0)
{
    const int bid = swz(blockIdx.x, 512);
    const int m  = bid * 16 + (threadIdx.x >> 4);
    const int c8 = (threadIdx.x & 15) * 8;
    const int b  = m >> 10;
    const int nnb = nn[m];
    const ushort* AFb  = AF  + ((size_t)b << 10) * H + c8;
    const ushort* ATWb = ATW + ((size_t)b << 10) * H + c8;
    const ushort* HBb  = HB  + ((size_t)b << 11) * H + c8;   // E = 2048
    const int* agm = ag + (size_t)m * NB;
    const int* bgm = bg + (size_t)m * NB;

    int2 ia0 = *(const int2*)(agm + 0), ib0 = *(const int2*)(bgm + 0);
    int2 ia1 = *(const int2*)(agm + 2), ib1 = *(const int2*)(bgm + 2);
    int2 ia2 = *(const int2*)(agm + 4), ib2 = *(const int2*)(bgm + 4);
    int2 ia3 = *(const int2*)(agm + 6), ib3 = *(const int2*)(bgm + 6);
    int2 ia4 = *(const int2*)(agm + 8), ib4 = *(const int2*)(bgm + 8);

    float sacc[8], facc[8];
    #pragma unroll
    for (int i = 0; i < 8; ++i) { sacc[i] = 0.f; facc[i] = 0.f; }

    #define GL_STEP(nb, ia, ib)                                          \
    if ((nb) < nnb) {                                                    \
        s16x8 av = *(const s16x8*)(AFb  + (size_t)(ia) * H);             \
        s16x8 tv = *(const s16x8*)(ATWb + (size_t)(ia) * H);             \
        s16x8 hv = *(const s16x8*)(HBb  + (size_t)(ib) * H);             \
        _Pragma("unroll")                                                \
        for (int i = 0; i < 8; ++i) {                                    \
            sacc[i] += b2f((ushort)av[i]);                               \
            facc[i] += b2f((ushort)tv[i]) * b2f((ushort)hv[i]);          \
        }                                                                \
    }
    GL_STEP(0, ia0.x, ib0.x) GL_STEP(1, ia0.y, ib0.y)
    GL_STEP(2, ia1.x, ib1.x) GL_STEP(3, ia1.y, ib1.y)
    GL_STEP(4, ia2.x, ib2.x) GL_STEP(5, ia2.y, ib2.y)
    GL_STEP(6, ia3.x, ib3.x) GL_STEP(7, ia3.y, ib3.y)
    GL_STEP(8, ia4.x, ib4.x) GL_STEP(9, ia4.y, ib4.y)
    #undef GL_STEP

    s16x8 so;
    #pragma unroll
    for (int i = 0; i < 8; ++i) so[i] = (short)f2b(sacc[i]);
    *(s16x8*)(SATOM + (size_t)m * H + c8) = so;

    const float nm = nmask[m];
    s16x8 sv = *(const s16x8*)(SLF + (size_t)m * H + c8);
    f32x4 lo, hi;
    #pragma unroll
    for (int i = 0; i < 4; ++i) {
        lo[i] = facc[i]     * b2f((ushort)sv[i])     * nm;
        hi[i] = facc[i + 4] * b2f((ushort)sv[i + 4]) * nm;
    }
    *(f32x4*)(out0 + (size_t)m * H + c8)     = lo;
    *(f32x4*)(out0 + (size_t)m * H + c8 + 4) = hi;
}

// ---------------------------------------------------------------------------
// FA GEMM body v2: Wa staged to LDS as bf16 transposed [128 cols][96 k]
// (block-cooperative, coalesced f32 reads) -> 6 ds_read_b128 per wave
// replaces 48 scalar global loads per thread.
// ---------------------------------------------------------------------------
__device__ __forceinline__ void fa_body(
    int tg, const float* __restrict__ ia, const float* __restrict__ Wa,
    ushort* sWa, ushort* __restrict__ Cb)
{
    // stage: Wa[82][128] f32 -> sWa[n][k] bf16, k in [0,96), pad k>=82 with 0
    for (int idx = threadIdx.x; idx < 82 * 128; idx += 256) {
        const int k = idx >> 7, n = idx & 127;
        sWa[n * 96 + k] = f2b(Wa[idx]);
    }
    for (int idx = threadIdx.x; idx < 14 * 128; idx += 256) {
        const int n = idx / 14, k = 82 + idx % 14;
        sWa[n * 96 + k] = 0;
    }
    __syncthreads();

    const int lane = threadIdx.x & 63, wid = threadIdx.x >> 6;
    const int l15 = lane & 15, g = lane >> 4;

    s16x8 w[2][3];
    #pragma unroll
    for (int ct = 0; ct < 2; ++ct) {
        const int n = (2 * wid + ct) * 16 + l15;
        #pragma unroll
        for (int kc = 0; kc < 3; ++kc)
            w[ct][kc] = *(const s16x8*)(sWa + n * 96 + kc * 32 + g * 8);
    }

    #pragma unroll
    for (int t = 0; t < 4; ++t) {
        const int m0 = (tg * 4 + t) * 16;
        const float* row = ia + (size_t)(m0 + l15) * 82;
        s16x8 a[3];
        #pragma unroll
        for (int kc = 0; kc < 3; ++kc) {
            #pragma unroll
            for (int p = 0; p < 4; ++p) {
                const int k = kc * 32 + g * 8 + 2 * p;     // even; boundary 82 even
                float2 v = (k < 82) ? *(const float2*)(row + k)
                                    : make_float2(0.f, 0.f);
                a[kc][2 * p]     = (short)f2b(v.x);
                a[kc][2 * p + 1] = (short)f2b(v.y);
            }
        }
        f32x4 acc[2];
        #pragma unroll
        for (int ct = 0; ct < 2; ++ct) acc[ct] = (f32x4){0.f, 0.f, 0.f, 0.f};
        #pragma unroll
        for (int kc = 0; kc < 3; ++kc)
            #pragma unroll
            for (int ct = 0; ct < 2; ++ct)
                acc[ct] = __builtin_amdgcn_mfma_f32_16x16x32_bf16(a[kc], w[ct][kc], acc[ct], 0, 0, 0);
        #pragma unroll
        for (int ct = 0; ct < 2; ++ct) {
            const int col = (2 * wid + ct) * 16 + l15;
            #pragma unroll
            for (int r = 0; r < 4; ++r)
                Cb[(size_t)(m0 + 4 * g + r) * H + col] = f2b(acc[ct][r]);
        }
    }
}

// ---------------------------------------------------------------------------
// K0: block-range-split {FA gemm | weights compose | FBS8 | HB}
//  [0,1024): FA  [1024,1296): weights  [1296,1552): FBS  [1552,2576): HB
//  HB v2: thread caches WnbR[6][8] in VGPRs, loops 8 rows (amortized weights)
// ---------------------------------------------------------------------------
__global__ __launch_bounds__(256, 4) void k0_prep_fa(
    const float* __restrict__ ia, const float* __restrict__ Wa,
    const float* __restrict__ Wna, const float* __restrict__ Ws,
    const float* __restrict__ Wu2, const float* __restrict__ bu2,
    const float* __restrict__ Wu1, const float* __restrict__ bu1,
    const float* __restrict__ bond, const int* __restrict__ bg,
    const int* __restrict__ nn, const float* __restrict__ Wnb,
    ushort* __restrict__ AF0, ushort* __restrict__ WTs,
    ushort* __restrict__ FBSb, ushort* __restrict__ HB)
{
    __shared__ ushort sWa[128 * 96];      // 24 KB (used by FA section only)
    const int bid = blockIdx.x;
    if (bid < 1024) {
        fa_body(swz(bid, 128), ia, Wa, sWa, AF0);
    } else if (bid < 1296) {
        int t = (bid - 1024) * 256 + threadIdx.x;
        const int tid = t;
        if (t < 128 * 128) { int n = t / 128, k = t % 128;
            WTs[tid] = f2b(Wna[k * H + n]); return; }
        t -= 128 * 128;
        if (t < 128 * 128) { int n = t / 128, k = t % 128;
            WTs[tid] = f2b(Ws[k * H + n]); return; }
        t -= 128 * 128;
        {
            const int n = t / 288, k = t % 288;
            float v = 0.f;
            if (k < 128) {
                v = Wu1[k * H + n];
            } else if (k < 256) {
                const int kk = k - 128;
                float s = 0.f;
                for (int j = 0; j < 128; ++j) s += Wu2[kk * H + j] * Wu1[(128 + j) * H + n];
                v = s;
            } else {
                const int j = k - 256;
                if (j < 6) {
                    float s = 0.f;
                    for (int q = 0; q < 128; ++q) s += Wu2[(128 + j) * H + q] * Wu1[(128 + q) * H + n];
                    v = s;
                } else if (j == 6) {
                    float s = 0.f;
                    for (int q = 0; q < 128; ++q) s += bu2[q] * Wu1[(128 + q) * H + n];
                    v = s;
                } else if (j == 7) {
                    v = bu1[n];
                }
            }
            WTs[tid] = f2b(v);
            return;
        }
    } else if (bid < 1552) {
        // FBS8[m][8] = bf16[ sum_nb bond[bg[m,nb]][0..5], num_nbs, 1 ]
        const int m = (bid - 1296) * 256 + threadIdx.x;
        const int b = m >> 10;
        const int nnb = nn[m];
        float s[6] = {0,0,0,0,0,0};
        for (int nb = 0; nb < nnb; ++nb) {
            const int ib = bg[m * NB + nb];
            const float* fb = bond + ((size_t)(b << 11) + (size_t)ib) * 6;
            #pragma unroll
            for (int j = 0; j < 6; ++j) s[j] += fb[j];
        }
        s16x8 o;
        #pragma unroll
        for (int j = 0; j < 6; ++j) o[j] = (short)f2b(s[j]);
        o[6] = (short)f2b((float)nnb);
        o[7] = (short)f2b(1.0f);
        *(s16x8*)(FBSb + (size_t)m * 8) = o;
    } else {
        // HB v2: block handles 128 rows; thread: col-group c8, 8 rows.
        const int c8 = (threadIdx.x & 15) * 8;
        const int rsub = threadIdx.x >> 4;             // 0..15
        const int rbase = (bid - 1552) * 128;
        float WnbR[6][8];
        #pragma unroll
        for (int j = 0; j < 6; ++j)
            #pragma unroll
            for (int i = 0; i < 8; ++i) WnbR[j][i] = Wnb[j * H + c8 + i];
        #pragma unroll
        for (int kq = 0; kq < 8; ++kq) {
            const int r = rbase + rsub + kq * 16;      // B*E rows total
            const float* fb = bond + (size_t)r * 6;
            const float2 f01 = *(const float2*)fb;
            const float2 f23 = *(const float2*)(fb + 2);
            const float2 f45 = *(const float2*)(fb + 4);
            s16x8 o;
            #pragma unroll
            for (int i = 0; i < 8; ++i) {
                const float v = f01.x * WnbR[0][i] + f01.y * WnbR[1][i]
                              + f23.x * WnbR[2][i] + f23.y * WnbR[3][i]
                              + f45.x * WnbR[4][i] + f45.y * WnbR[5][i];
                o[i] = (short)f2b(v);
            }
            *(s16x8*)(HB + (size_t)r * H + c8) = o;
        }
    }
}

// ---------------------------------------------------------------------------
extern "C" void kernel_launch(void* const* d_in, const int* in_sizes, int n_in,
                              void* d_out, int out_size, void* d_ws, size_t ws_size,
                              hipStream_t stream)
{
    (void)in_sizes; (void)n_in; (void)out_size; (void)ws_size;

    const float* input_atom = (const float*)d_in[0];
    const float* input_bond = (const float*)d_in[1];
    const int*   atom_graph = (const int*)d_in[2];
    const int*   bond_graph = (const int*)d_in[3];
    const int*   num_nbs    = (const int*)d_in[4];
    const float* node_mask  = (const float*)d_in[5];
    const float* W_atom     = (const float*)d_in[6];
    const float* W_nei_atom = (const float*)d_in[7];
    const float* W_nei_bond = (const float*)d_in[8];
    const float* W_self     = (const float*)d_in[9];
    const float* W_U2       = (const float*)d_in[10];
    const float* b_U2       = (const float*)d_in[11];
    const float* W_U1       = (const float*)d_in[12];
    const float* b_U1       = (const float*)d_in[13];

    char* ws = (char*)d_ws;
    const size_t MB = 1024 * 1024;
    ushort* AF0   = (ushort*)(ws);               // [0,16) MB
    ushort* AF1   = (ushort*)(ws + 16 * MB);     // [16,32) MB (SLF at last depth)
    ushort* SATw  = (ushort*)(ws + 32 * MB);     // [32,48) MB (ATW at last depth)
    ushort* ATW   = SATw;
    ushort* HB    = (ushort*)(ws + 64 * MB);     // [64,96) MB
    ushort* SATl  = (ushort*)(ws + 96 * MB);     // [96,112) MB
    ushort* FBSb  = (ushort*)(ws + 112 * MB);    // 1 MB
    ushort* WTs_  = (ushort*)(ws + 113 * MB);    // ~140 KB

    ushort* WTna  = WTs_;                        // [128][128]
    ushort* WTslf = WTna  + 128 * 128;           // [128][128]
    ushort* WTu1f = WTslf + 128 * 128;           // [128][288]

    float*  out0  = (float*)d_out;               // kernel [M][128] f32
    float*  out1  = out0 + SL;                   // atom_features [M][128] f32
    ushort* SLF   = AF1;                         // AF@Wslf (bf16), AF1 dead

    // K0: FA gemm || weights compose || FBS || HB
    k0_prep_fa<<<2576, 256, 0, stream>>>(input_atom, W_atom, W_nei_atom,
                                         W_self, W_U2, b_U2, W_U1, b_U1,
                                         input_bond, bond_graph, num_nbs,
                                         W_nei_bond, AF0, WTs_, FBSb, HB);

    // depth 0
    gather_satom<<<4096, 256, 0, stream>>>(AF0, atom_graph, num_nbs, SATw);
    u1f<false><<<1024, 256, 0, stream>>>(AF0, SATw, FBSb, WTu1f, nullptr, AF1);
    // depth 1
    gather_satom<<<4096, 256, 0, stream>>>(AF1, atom_graph, num_nbs, SATw);
    u1f<false><<<1024, 256, 0, stream>>>(AF1, SATw, FBSb, WTu1f, nullptr, AF0);

    // ---- last depth (AF = AF0; AF1 dead -> SLF; SATw -> ATW) ----
    k5_atw_slf<<<2048, 256, 0, stream>>>(AF0, WTna, WTslf, ATW, SLF);
    gather_last2<<<4096, 256, 0, stream>>>(AF0, ATW, HB, SLF, node_mask,
                                           atom_graph, bond_graph, num_nbs,
                                           SATl, out0);
    // atom_features -> out1 (f32)
    u1f<true><<<1024, 256, 0, stream>>>(AF0, SATl, FBSb, WTu1f, out1, nullptr);
}